// Round 10
// baseline (438.517 us; speedup 1.0000x reference)
//
#include <hip/hip_runtime.h>

#define N_NODES 50000
#define E_EDGES 800000
#define D_FEAT  96
#define C_CLS   40
#define N_ITER  8

#define NCHUNK 49          // ceil(50000/1024) node chunks
#define NB     256         // edge-partition blocks
#define EPB    3125        // edges per block (256*3125 = 800000 exactly)

#define PLANE  ((size_t)N_NODES * 64)   // one 48-col fp8 plane, 64B-padded rows

typedef short bf16x8 __attribute__((ext_vector_type(8)));
typedef float f32x4  __attribute__((ext_vector_type(4)));
typedef float f32x2  __attribute__((ext_vector_type(2)));

#if defined(__has_builtin)
#if __has_builtin(__builtin_amdgcn_cvt_pk_f32_fp8) && __has_builtin(__builtin_amdgcn_cvt_pk_fp8_f32)
#define HAVE_FP8_CVT 1
#endif
#endif
#ifndef HAVE_FP8_CVT
#define HAVE_FP8_CVT 0
#endif

// bf16 helpers (RNE)
static __device__ __forceinline__ unsigned short f2bf(float f) {
    unsigned u = __float_as_uint(f);
    u = (u + 0x7FFF + ((u >> 16) & 1)) >> 16;
    return (unsigned short)u;
}

// ---- fp8 e4m3fn manual fallback ----
static __device__ __forceinline__ unsigned f32_to_fp8_manual(float f) {
    unsigned u = __float_as_uint(f);
    unsigned s = u >> 31;
    int e8 = (int)((u >> 23) & 0xFF) - 127 + 7;
    unsigned m23 = u & 0x7FFFFF;
    if (e8 <= 0) return s << 7;
    if (e8 >= 15) return (s << 7) | 0x7E;
    unsigned m = m23 >> 20;
    unsigned rem = m23 & 0xFFFFF;
    if (rem > 0x80000u || (rem == 0x80000u && (m & 1))) {
        m++;
        if (m == 8) { m = 0; e8++; if (e8 >= 15) return (s << 7) | 0x7E; }
    }
    return (s << 7) | ((unsigned)e8 << 3) | m;
}
static __device__ __forceinline__ float fp8_to_f32_manual(unsigned b) {
    unsigned s = (b >> 7) & 1, e = (b >> 3) & 0xF, m = b & 7;
    if (e == 0) return 0.0f;
    return __uint_as_float((s << 31) | ((e + 120) << 23) | (m << 20));
}
static __device__ __forceinline__ void fp8x4_dec(unsigned w, float* o) {
#if HAVE_FP8_CVT
    f32x2 lo = __builtin_amdgcn_cvt_pk_f32_fp8(w, false);
    f32x2 hi = __builtin_amdgcn_cvt_pk_f32_fp8(w, true);
    o[0] = lo[0]; o[1] = lo[1]; o[2] = hi[0]; o[3] = hi[1];
#else
    o[0] = fp8_to_f32_manual(w & 0xFF);
    o[1] = fp8_to_f32_manual((w >> 8) & 0xFF);
    o[2] = fp8_to_f32_manual((w >> 16) & 0xFF);
    o[3] = fp8_to_f32_manual((w >> 24) & 0xFF);
#endif
}
static __device__ __forceinline__ unsigned fp8x4_enc(float a, float b, float c, float d) {
#if HAVE_FP8_CVT
    unsigned w = __builtin_amdgcn_cvt_pk_fp8_f32(a, b, 0, false);
    w = __builtin_amdgcn_cvt_pk_fp8_f32(c, d, (int)w, true);
    return w;
#else
    return f32_to_fp8_manual(a) | (f32_to_fp8_manual(b) << 8) |
           (f32_to_fp8_manual(c) << 16) | (f32_to_fp8_manual(d) << 24);
#endif
}

// decode 8 fp8 (uint2) and accumulate
static __device__ __forceinline__ void fma8(uint2 r, float v, float* acc) {
    float f[8];
    fp8x4_dec(r.x, f);
    fp8x4_dec(r.y, f + 4);
    #pragma unroll
    for (int j = 0; j < 8; ++j) acc[j] = fmaf(f[j], v, acc[j]);
}

// ---------------------------------------------------------------------------
// CSR phase A: per-block LDS histogram over 49 node-chunks -> cm[c*NB + b]
// ---------------------------------------------------------------------------
__global__ __launch_bounds__(256) void k_count(const int* __restrict__ erow,
                                               int* __restrict__ cm) {
    __shared__ int lcnt[NCHUNK];
    int b = blockIdx.x, tid = threadIdx.x;
    if (tid < NCHUNK) lcnt[tid] = 0;
    __syncthreads();
    int base = b * EPB;
    for (int i = tid; i < EPB; i += 256)
        atomicAdd(&lcnt[erow[base + i] >> 10], 1);
    __syncthreads();
    if (tid < NCHUNK) cm[tid * NB + b] = lcnt[tid];
}

// ---------------------------------------------------------------------------
// CSR phase B: in-place exclusive scan of cm (12544 ints), one block
// ---------------------------------------------------------------------------
__global__ __launch_bounds__(1024) void k_cscan(int* __restrict__ cm) {
    __shared__ int sb[1024];
    const int TOT = NCHUNK * NB;
    const int PER = 13;
    int tid = threadIdx.x;
    int base = tid * PER;
    int v[PER];
    int s = 0;
    #pragma unroll
    for (int j = 0; j < PER; ++j) {
        int idx = base + j;
        v[j] = (idx < TOT) ? cm[idx] : 0;
        s += v[j];
    }
    sb[tid] = s;
    __syncthreads();
    for (int d = 1; d < 1024; d <<= 1) {
        int t = (tid >= d) ? sb[tid - d] : 0;
        __syncthreads();
        sb[tid] += t;
        __syncthreads();
    }
    int ex = sb[tid] - s;
    #pragma unroll
    for (int j = 0; j < PER; ++j) {
        int idx = base + j;
        if (idx < TOT) { cm[idx] = ex; ex += v[j]; }
    }
}

// ---------------------------------------------------------------------------
// CSR phase C: scatter (colval, rowlocal) into chunk-major staging runs
// ---------------------------------------------------------------------------
__global__ __launch_bounds__(256) void k_scatter_runs(const int* __restrict__ erow,
                                                      const int* __restrict__ ecol,
                                                      const float* __restrict__ ev,
                                                      const int* __restrict__ cm,
                                                      int2* __restrict__ stag) {
    __shared__ int lcur[NCHUNK];
    int b = blockIdx.x, tid = threadIdx.x;
    if (tid < NCHUNK) lcur[tid] = cm[tid * NB + b];
    __syncthreads();
    int base = b * EPB;
    for (int i = tid; i < EPB; i += 256) {
        int e = base + i;
        int r = erow[e];
        int c = r >> 10;
        int pos = atomicAdd(&lcur[c], 1);
        int2 s;
        s.x = (int)((unsigned)(ecol[e] & 0xFFFF) | ((unsigned)f2bf(ev[e]) << 16));
        s.y = r & 1023;
        stag[pos] = s;
    }
}

// ---------------------------------------------------------------------------
// CSR phase D: per-chunk LDS histogram -> scan -> off[] + row-grouped epk
// ---------------------------------------------------------------------------
__global__ __launch_bounds__(1024) void k_chunk_csr(const int2* __restrict__ stag,
                                                    const int* __restrict__ cm,
                                                    unsigned* __restrict__ epk,
                                                    int* __restrict__ off) {
    __shared__ int lh[1024];
    __shared__ int lex[1024];
    __shared__ int sb[1024];
    int c = blockIdx.x, tid = threadIdx.x;
    int cb = cm[c * NB];
    int ce = (c + 1 < NCHUNK) ? cm[(c + 1) * NB] : E_EDGES;
    int m = ce - cb;

    lh[tid] = 0;
    __syncthreads();
    for (int i = tid; i < m; i += 1024) {
        int2 s = stag[cb + i];
        atomicAdd(&lh[s.y], 1);
    }
    __syncthreads();
    int v = lh[tid];
    sb[tid] = v;
    __syncthreads();
    for (int d = 1; d < 1024; d <<= 1) {
        int t = (tid >= d) ? sb[tid - d] : 0;
        __syncthreads();
        sb[tid] += t;
        __syncthreads();
    }
    int ex = sb[tid] - v;
    lex[tid] = ex;
    int node = c * 1024 + tid;
    if (node < N_NODES) off[node] = cb + ex;
    if (c == NCHUNK - 1 && tid == 0) off[N_NODES] = E_EDGES;
    __syncthreads();
    for (int i = tid; i < m; i += 1024) {
        int2 s = stag[cb + i];
        int pos = atomicAdd(&lex[s.y], 1);
        epk[cb + pos] = (unsigned)s.x;
    }
}

// ---------------------------------------------------------------------------
// One-time: repack W_gc into MFMA B-fragment order, bf16.
// ---------------------------------------------------------------------------
__global__ __launch_bounds__(256) void k_prep_w(const float* __restrict__ W,
                                                unsigned short* __restrict__ WB) {
    for (int idx = threadIdx.x; idx < 18 * 64; idx += 256) {
        int grp = idx >> 6;
        int lane = idx & 63;
        int t = grp / 3, s = grp - t * 3;
        int n = t * 16 + (lane & 15);
        int k0 = s * 32 + (lane >> 4) * 8;
        unsigned short* dst = WB + (size_t)idx * 8;
        #pragma unroll
        for (int j = 0; j < 8; ++j)
            dst[j] = f2bf(W[(k0 + j) * D_FEAT + n]);
    }
}

// ---------------------------------------------------------------------------
// One-time: f32 -> bf16 row conversion (x at iteration 0)
// ---------------------------------------------------------------------------
__global__ __launch_bounds__(256) void k_cvt_bf16(const float* __restrict__ src,
                                                  unsigned short* __restrict__ dst,
                                                  int n8) {
    int g = blockIdx.x * 256 + threadIdx.x;
    if (g >= n8) return;
    const float4* s4 = (const float4*)src + (size_t)g * 2;
    float4 x0 = s4[0], x1 = s4[1];
    float vals[8] = {x0.x, x0.y, x0.z, x0.w, x1.x, x1.y, x1.z, x1.w};
    uint4 pk; unsigned* pku = (unsigned*)&pk;
    #pragma unroll
    for (int w2 = 0; w2 < 4; ++w2) {
        unsigned lo = f2bf(vals[w2 * 2 + 0]);
        unsigned hi = f2bf(vals[w2 * 2 + 1]);
        pku[w2] = lo | (hi << 16);
    }
    *(uint4*)(dst + (size_t)g * 8) = pk;
}

// ---------------------------------------------------------------------------
// Kernel 1: support(fp8, two 48-col planes with 64B-padded rows) =
//           hb(bf16) @ WB(bf16) via MFMA 16x16x32.
// ---------------------------------------------------------------------------
__global__ __launch_bounds__(256) void k_matmul_mfma(
        const unsigned short* __restrict__ hb,
        const unsigned short* __restrict__ WB,
        unsigned char* __restrict__ supp) {
    __shared__ float sm[64 * 100];
    int tid = threadIdx.x;
    int wave = tid >> 6, lane = tid & 63;
    int q = lane >> 4, c = lane & 15;
    int m0 = blockIdx.x * 64 + wave * 16;

    if (m0 < N_NODES) {
        const unsigned short* arow = hb + (size_t)(m0 + c) * D_FEAT + q * 8;
        bf16x8 a0 = *(const bf16x8*)(arow);
        bf16x8 a1 = *(const bf16x8*)(arow + 32);
        bf16x8 a2 = *(const bf16x8*)(arow + 64);
        #pragma unroll
        for (int t = 0; t < 6; ++t) {
            const unsigned short* bp = WB + ((size_t)(t * 3) * 64 + lane) * 8;
            bf16x8 b0 = *(const bf16x8*)(bp);
            bf16x8 b1 = *(const bf16x8*)(bp + 64 * 8);
            bf16x8 b2 = *(const bf16x8*)(bp + 128 * 8);
            f32x4 acc = {0.f, 0.f, 0.f, 0.f};
            acc = __builtin_amdgcn_mfma_f32_16x16x32_bf16(a0, b0, acc, 0, 0, 0);
            acc = __builtin_amdgcn_mfma_f32_16x16x32_bf16(a1, b1, acc, 0, 0, 0);
            acc = __builtin_amdgcn_mfma_f32_16x16x32_bf16(a2, b2, acc, 0, 0, 0);
            #pragma unroll
            for (int r = 0; r < 4; ++r)
                sm[(wave * 16 + q * 4 + r) * 100 + t * 16 + c] = acc[r];
        }
    }
    __syncthreads();

    // 64 rows x 2 planes x 3 uint4 (16 fp8 cols) = 384 stores
    for (int o = tid; o < 384; o += 256) {
        int row = o / 6;
        int rem = o - row * 6;
        int plane = rem / 3;
        int q3 = rem - plane * 3;
        int grow = blockIdx.x * 64 + row;
        if (grow < N_NODES) {
            const float* sp = sm + row * 100 + plane * 48 + q3 * 16;
            uint4 pk;
            pk.x = fp8x4_enc(sp[0],  sp[1],  sp[2],  sp[3]);
            pk.y = fp8x4_enc(sp[4],  sp[5],  sp[6],  sp[7]);
            pk.z = fp8x4_enc(sp[8],  sp[9],  sp[10], sp[11]);
            pk.w = fp8x4_enc(sp[12], sp[13], sp[14], sp[15]);
            *(uint4*)(supp + (size_t)plane * PLANE + (size_t)grow * 64 + q3 * 16) = pk;
        }
    }
}

// ---------------------------------------------------------------------------
// Kernel 2 (fused agg+combine), HALF-PASS over 48 feature cols.
// 6 threads/node, 8 fp8 cols (uint2 load, one cacheline/edge) each.
// plane = L2-resident 3.2MB buffer. Software-pipelined edge loop.
// pc = 0 or 48 (global col base for h/b/out).
// ---------------------------------------------------------------------------
__global__ __launch_bounds__(192) void k_agg_half(const int* __restrict__ off,
                                                  const unsigned* __restrict__ epk,
                                                  const unsigned char* __restrict__ plane,
                                                  const unsigned short* hin,
                                                  const float* __restrict__ b,
                                                  unsigned short* hout,
                                                  int pc) {
    int gid = blockIdx.x * 192 + threadIdx.x;
    int n = gid / 6;
    int q = gid % 6;             // 8-col group within the 48-col plane
    if (n >= N_NODES) return;

    int s = off[n];
    int e = off[n + 1];

    float acc[8];
    #pragma unroll
    for (int j = 0; j < 8; ++j) acc[j] = 0.0f;

    const int qb = q * 8;        // byte offset in 64B row

    int i = s;
    // scalar prologue to 4-edge alignment
    for (; i < e && (i & 3); ++i) {
        unsigned p = epk[i];
        float v = __uint_as_float(p & 0xFFFF0000u);
        uint2 r = *(const uint2*)(plane + (size_t)(p & 0xFFFFu) * 64 + qb);
        fma8(r, v, acc);
    }
    int ng = (e - i) >> 2;
    if (ng > 0) {
        uint4 pq = *(const uint4*)(epk + i);
        uint2 c0 = *(const uint2*)(plane + (size_t)(pq.x & 0xFFFFu) * 64 + qb);
        uint2 c1 = *(const uint2*)(plane + (size_t)(pq.y & 0xFFFFu) * 64 + qb);
        uint2 c2 = *(const uint2*)(plane + (size_t)(pq.z & 0xFFFFu) * 64 + qb);
        uint2 c3 = *(const uint2*)(plane + (size_t)(pq.w & 0xFFFFu) * 64 + qb);
        float v0 = __uint_as_float(pq.x & 0xFFFF0000u);
        float v1 = __uint_as_float(pq.y & 0xFFFF0000u);
        float v2 = __uint_as_float(pq.z & 0xFFFF0000u);
        float v3 = __uint_as_float(pq.w & 0xFFFF0000u);
        for (int g = 1; g < ng; ++g) {
            uint4 pq2 = *(const uint4*)(epk + i + 4 * g);
            uint2 n0 = *(const uint2*)(plane + (size_t)(pq2.x & 0xFFFFu) * 64 + qb);
            uint2 n1 = *(const uint2*)(plane + (size_t)(pq2.y & 0xFFFFu) * 64 + qb);
            uint2 n2 = *(const uint2*)(plane + (size_t)(pq2.z & 0xFFFFu) * 64 + qb);
            uint2 n3 = *(const uint2*)(plane + (size_t)(pq2.w & 0xFFFFu) * 64 + qb);
            fma8(c0, v0, acc); fma8(c1, v1, acc);
            fma8(c2, v2, acc); fma8(c3, v3, acc);
            c0 = n0; c1 = n1; c2 = n2; c3 = n3;
            v0 = __uint_as_float(pq2.x & 0xFFFF0000u);
            v1 = __uint_as_float(pq2.y & 0xFFFF0000u);
            v2 = __uint_as_float(pq2.z & 0xFFFF0000u);
            v3 = __uint_as_float(pq2.w & 0xFFFF0000u);
        }
        fma8(c0, v0, acc); fma8(c1, v1, acc);
        fma8(c2, v2, acc); fma8(c3, v3, acc);
        i += 4 * ng;
    }
    // scalar tail
    for (; i < e; ++i) {
        unsigned p = epk[i];
        float v = __uint_as_float(p & 0xFFFF0000u);
        uint2 r = *(const uint2*)(plane + (size_t)(p & 0xFFFFu) * 64 + qb);
        fma8(r, v, acc);
    }

    // skip + bias + relu on this thread's 8 global cols
    int col = pc + qb;
    uint4 hq = *(const uint4*)(hin + (size_t)n * D_FEAT + col);
    const unsigned* hu = (const unsigned*)&hq;
    const float* brow = b + col;
    float og[8];
    #pragma unroll
    for (int w2 = 0; w2 < 4; ++w2) {
        float h0 = __uint_as_float(hu[w2] << 16);
        float h1 = __uint_as_float(hu[w2] & 0xFFFF0000u);
        og[w2*2+0] = fmaxf(0.5f * h0 + 0.5f * (acc[w2*2+0] + brow[w2*2+0]), 0.0f);
        og[w2*2+1] = fmaxf(0.5f * h1 + 0.5f * (acc[w2*2+1] + brow[w2*2+1]), 0.0f);
    }
    uint4 pk; unsigned* pku = (unsigned*)&pk;
    #pragma unroll
    for (int w2 = 0; w2 < 4; ++w2)
        pku[w2] = (unsigned)f2bf(og[w2*2+0]) | ((unsigned)f2bf(og[w2*2+1]) << 16);
    *(uint4*)(hout + (size_t)n * D_FEAT + col) = pk;
}

// ---------------------------------------------------------------------------
// Kernel 3: logits = bf16dec(hb) @ W_lin ; out = log_softmax (f32 math)
// ---------------------------------------------------------------------------
__global__ __launch_bounds__(256) void k_final(const unsigned short* __restrict__ hb,
                                               const float* __restrict__ Wg,
                                               float* __restrict__ out) {
    __shared__ float Wl[D_FEAT * C_CLS];
    {
        const float4* src = (const float4*)Wg;
        float4* dst = (float4*)Wl;
        for (int i = threadIdx.x; i < 960; i += 256) dst[i] = src[i];
    }
    __syncthreads();

    int n = blockIdx.x * 256 + threadIdx.x;
    if (n >= N_NODES) return;

    float acc[C_CLS];
    #pragma unroll
    for (int c = 0; c < C_CLS; ++c) acc[c] = 0.0f;

    const unsigned short* hrow = hb + (size_t)n * D_FEAT;
    for (int g = 0; g < 12; ++g) {
        uint4 hq = *(const uint4*)(hrow + g * 8);
        const unsigned* hu = (const unsigned*)&hq;
        float hv[8];
        #pragma unroll
        for (int w2 = 0; w2 < 4; ++w2) {
            hv[w2*2+0] = __uint_as_float(hu[w2] << 16);
            hv[w2*2+1] = __uint_as_float(hu[w2] & 0xFFFF0000u);
        }
        #pragma unroll
        for (int kk = 0; kk < 8; ++kk) {
            float hs = hv[kk];
            const float* wr = &Wl[(g * 8 + kk) * C_CLS];
            #pragma unroll
            for (int c4 = 0; c4 < 10; ++c4) {
                float4 w = *(const float4*)(wr + c4 * 4);
                acc[c4 * 4 + 0] = fmaf(hs, w.x, acc[c4 * 4 + 0]);
                acc[c4 * 4 + 1] = fmaf(hs, w.y, acc[c4 * 4 + 1]);
                acc[c4 * 4 + 2] = fmaf(hs, w.z, acc[c4 * 4 + 2]);
                acc[c4 * 4 + 3] = fmaf(hs, w.w, acc[c4 * 4 + 3]);
            }
        }
    }

    float m = acc[0];
    #pragma unroll
    for (int c = 1; c < C_CLS; ++c) m = fmaxf(m, acc[c]);
    float s = 0.0f;
    #pragma unroll
    for (int c = 0; c < C_CLS; ++c) s += expf(acc[c] - m);
    float lse = m + logf(s);

    float* orow = out + (size_t)n * C_CLS;
    #pragma unroll
    for (int c4 = 0; c4 < 10; ++c4)
        *(float4*)(orow + c4 * 4) =
            make_float4(acc[c4 * 4 + 0] - lse, acc[c4 * 4 + 1] - lse,
                        acc[c4 * 4 + 2] - lse, acc[c4 * 4 + 3] - lse);
}

// ---------------------------------------------------------------------------
static inline size_t align256(size_t x) { return (x + 255) & ~(size_t)255; }

extern "C" void kernel_launch(void* const* d_in, const int* in_sizes, int n_in,
                              void* d_out, int out_size, void* d_ws, size_t ws_size,
                              hipStream_t stream) {
    const float* x    = (const float*)d_in[0];
    const int*   erow = (const int*)  d_in[1];
    const int*   ecol = (const int*)  d_in[2];
    const float* ev   = (const float*)d_in[3];
    const float* Wgc  = (const float*)d_in[4];
    const float* bgc  = (const float*)d_in[5];
    const float* Wlin = (const float*)d_in[6];
    float* out = (float*)d_out;

    const size_t NF = (size_t)N_NODES * D_FEAT;
    char* ws = (char*)d_ws;
    unsigned short* hb         = (unsigned short*)ws; ws += align256(NF * 2);              // 9.6 MB
    unsigned short* xb         = (unsigned short*)ws; ws += align256(NF * 2);              // 9.6 MB
    unsigned char*  supp       = (unsigned char*)ws;  ws += align256(2 * PLANE);           // 6.4 MB
    unsigned*       epk        = (unsigned*)ws;       ws += align256((size_t)E_EDGES * 4); // 3.2 MB
    int2*           stag       = (int2*)ws;           ws += align256((size_t)E_EDGES * 8); // 6.4 MB
    unsigned short* WB         = (unsigned short*)ws; ws += align256((size_t)18 * 64 * 8 * 2);
    int*            off        = (int*)ws;            ws += align256((size_t)(N_NODES + 1) * 4);
    int*            cm         = (int*)ws;            ws += align256((size_t)NCHUNK * NB * 4);

    // ---- one-time prep + atomic-free CSR build ----
    k_prep_w      <<<1, 256, 0, stream>>>(Wgc, WB);
    k_cvt_bf16    <<<(int)((NF / 8 + 255) / 256), 256, 0, stream>>>(x, xb, (int)(NF / 8));
    k_count       <<<NB, 256, 0, stream>>>(erow, cm);
    k_cscan       <<<1, 1024, 0, stream>>>(cm);
    k_scatter_runs<<<NB, 256, 0, stream>>>(erow, ecol, ev, cm, stag);
    k_chunk_csr   <<<NCHUNK, 1024, 0, stream>>>(stag, cm, epk, off);

    // ---- 8 GCN iterations (bf16 state hb, in-place) ----
    const int g_mm = (N_NODES + 63) / 64;
    const int g_ag = (N_NODES * 6 + 191) / 192;
    for (int it = 0; it < N_ITER; ++it) {
        const unsigned short* hin = (it == 0) ? xb : hb;
        k_matmul_mfma<<<g_mm, 256, 0, stream>>>(hin, WB, supp);
        k_agg_half   <<<g_ag, 192, 0, stream>>>(off, epk, supp,         hin, bgc, hb, 0);
        k_agg_half   <<<g_ag, 192, 0, stream>>>(off, epk, supp + PLANE, hin, bgc, hb, 48);
    }
    k_final<<<(N_NODES + 255) / 256, 256, 0, stream>>>(hb, Wlin, out);
}

// Round 11
// 394.323 us; speedup vs baseline: 1.1121x; 1.1121x over previous
//
#include <hip/hip_runtime.h>

#define N_NODES 50000
#define E_EDGES 800000
#define D_FEAT  96
#define C_CLS   40
#define N_ITER  8

#define NCHUNK 49          // ceil(50000/1024) node chunks
#define NB     256         // edge-partition blocks
#define EPB    3125        // edges per block (256*3125 = 800000 exactly)

typedef short bf16x8 __attribute__((ext_vector_type(8)));
typedef float f32x4  __attribute__((ext_vector_type(4)));
typedef float f32x2  __attribute__((ext_vector_type(2)));

#if defined(__has_builtin)
#if __has_builtin(__builtin_amdgcn_cvt_pk_f32_fp8) && __has_builtin(__builtin_amdgcn_cvt_pk_fp8_f32)
#define HAVE_FP8_CVT 1
#endif
#endif
#ifndef HAVE_FP8_CVT
#define HAVE_FP8_CVT 0
#endif

// bf16 helpers (RNE)
static __device__ __forceinline__ unsigned short f2bf(float f) {
    unsigned u = __float_as_uint(f);
    u = (u + 0x7FFF + ((u >> 16) & 1)) >> 16;
    return (unsigned short)u;
}

// ---- fp8 e4m3fn manual fallback ----
static __device__ __forceinline__ unsigned f32_to_fp8_manual(float f) {
    unsigned u = __float_as_uint(f);
    unsigned s = u >> 31;
    int e8 = (int)((u >> 23) & 0xFF) - 127 + 7;
    unsigned m23 = u & 0x7FFFFF;
    if (e8 <= 0) return s << 7;
    if (e8 >= 15) return (s << 7) | 0x7E;
    unsigned m = m23 >> 20;
    unsigned rem = m23 & 0xFFFFF;
    if (rem > 0x80000u || (rem == 0x80000u && (m & 1))) {
        m++;
        if (m == 8) { m = 0; e8++; if (e8 >= 15) return (s << 7) | 0x7E; }
    }
    return (s << 7) | ((unsigned)e8 << 3) | m;
}
static __device__ __forceinline__ float fp8_to_f32_manual(unsigned b) {
    unsigned s = (b >> 7) & 1, e = (b >> 3) & 0xF, m = b & 7;
    if (e == 0) return 0.0f;
    return __uint_as_float((s << 31) | ((e + 120) << 23) | (m << 20));
}
static __device__ __forceinline__ void fp8x4_dec(unsigned w, float* o) {
#if HAVE_FP8_CVT
    f32x2 lo = __builtin_amdgcn_cvt_pk_f32_fp8(w, false);
    f32x2 hi = __builtin_amdgcn_cvt_pk_f32_fp8(w, true);
    o[0] = lo[0]; o[1] = lo[1]; o[2] = hi[0]; o[3] = hi[1];
#else
    o[0] = fp8_to_f32_manual(w & 0xFF);
    o[1] = fp8_to_f32_manual((w >> 8) & 0xFF);
    o[2] = fp8_to_f32_manual((w >> 16) & 0xFF);
    o[3] = fp8_to_f32_manual((w >> 24) & 0xFF);
#endif
}
static __device__ __forceinline__ unsigned fp8x4_enc(float a, float b, float c, float d) {
#if HAVE_FP8_CVT
    unsigned w = __builtin_amdgcn_cvt_pk_fp8_f32(a, b, 0, false);
    w = __builtin_amdgcn_cvt_pk_fp8_f32(c, d, (int)w, true);
    return w;
#else
    return f32_to_fp8_manual(a) | (f32_to_fp8_manual(b) << 8) |
           (f32_to_fp8_manual(c) << 16) | (f32_to_fp8_manual(d) << 24);
#endif
}

// ---------------------------------------------------------------------------
// CSR phase A: per-block LDS histogram over 49 node-chunks -> cm[c*NB + b]
// ---------------------------------------------------------------------------
__global__ __launch_bounds__(256) void k_count(const int* __restrict__ erow,
                                               int* __restrict__ cm) {
    __shared__ int lcnt[NCHUNK];
    int b = blockIdx.x, tid = threadIdx.x;
    if (tid < NCHUNK) lcnt[tid] = 0;
    __syncthreads();
    int base = b * EPB;
    for (int i = tid; i < EPB; i += 256)
        atomicAdd(&lcnt[erow[base + i] >> 10], 1);
    __syncthreads();
    if (tid < NCHUNK) cm[tid * NB + b] = lcnt[tid];
}

// ---------------------------------------------------------------------------
// CSR phase B: in-place exclusive scan of cm (12544 ints), one block
// ---------------------------------------------------------------------------
__global__ __launch_bounds__(1024) void k_cscan(int* __restrict__ cm) {
    __shared__ int sb[1024];
    const int TOT = NCHUNK * NB;
    const int PER = 13;
    int tid = threadIdx.x;
    int base = tid * PER;
    int v[PER];
    int s = 0;
    #pragma unroll
    for (int j = 0; j < PER; ++j) {
        int idx = base + j;
        v[j] = (idx < TOT) ? cm[idx] : 0;
        s += v[j];
    }
    sb[tid] = s;
    __syncthreads();
    for (int d = 1; d < 1024; d <<= 1) {
        int t = (tid >= d) ? sb[tid - d] : 0;
        __syncthreads();
        sb[tid] += t;
        __syncthreads();
    }
    int ex = sb[tid] - s;
    #pragma unroll
    for (int j = 0; j < PER; ++j) {
        int idx = base + j;
        if (idx < TOT) { cm[idx] = ex; ex += v[j]; }
    }
}

// ---------------------------------------------------------------------------
// CSR phase C: scatter (colval, rowlocal) into chunk-major staging runs
// ---------------------------------------------------------------------------
__global__ __launch_bounds__(256) void k_scatter_runs(const int* __restrict__ erow,
                                                      const int* __restrict__ ecol,
                                                      const float* __restrict__ ev,
                                                      const int* __restrict__ cm,
                                                      int2* __restrict__ stag) {
    __shared__ int lcur[NCHUNK];
    int b = blockIdx.x, tid = threadIdx.x;
    if (tid < NCHUNK) lcur[tid] = cm[tid * NB + b];
    __syncthreads();
    int base = b * EPB;
    for (int i = tid; i < EPB; i += 256) {
        int e = base + i;
        int r = erow[e];
        int c = r >> 10;
        int pos = atomicAdd(&lcur[c], 1);
        int2 s;
        s.x = (int)((unsigned)(ecol[e] & 0xFFFF) | ((unsigned)f2bf(ev[e]) << 16));
        s.y = r & 1023;
        stag[pos] = s;
    }
}

// ---------------------------------------------------------------------------
// CSR phase D: per-chunk LDS histogram -> scan -> off[] + row-grouped epk,
// PLUS within-chunk degree-sorted node permutation (LDS bins, no global
// atomics; preserves chunk locality for off/h while equalizing wave degrees).
// ---------------------------------------------------------------------------
__global__ __launch_bounds__(1024) void k_chunk_csr(const int2* __restrict__ stag,
                                                    const int* __restrict__ cm,
                                                    unsigned* __restrict__ epk,
                                                    int* __restrict__ off,
                                                    int* __restrict__ perm) {
    __shared__ int lh[1024];
    __shared__ int lex[1024];
    __shared__ int sb[1024];
    __shared__ int dh2[64];
    int c = blockIdx.x, tid = threadIdx.x;
    int cb = cm[c * NB];
    int ce = (c + 1 < NCHUNK) ? cm[(c + 1) * NB] : E_EDGES;
    int m = ce - cb;

    lh[tid] = 0;
    if (tid < 64) dh2[tid] = 0;
    __syncthreads();
    for (int i = tid; i < m; i += 1024) {
        int2 s = stag[cb + i];
        atomicAdd(&lh[s.y], 1);
    }
    __syncthreads();
    int v = lh[tid];
    sb[tid] = v;
    __syncthreads();
    for (int d = 1; d < 1024; d <<= 1) {
        int t = (tid >= d) ? sb[tid - d] : 0;
        __syncthreads();
        sb[tid] += t;
        __syncthreads();
    }
    int ex = sb[tid] - v;
    lex[tid] = ex;
    int node = c * 1024 + tid;
    bool valid = node < N_NODES;
    if (valid) off[node] = cb + ex;
    if (c == NCHUNK - 1 && tid == 0) off[N_NODES] = E_EDGES;

    // within-chunk degree-bin sort -> perm
    int bin = min(v, 63);
    __syncthreads();
    if (valid) atomicAdd(&dh2[bin], 1);
    __syncthreads();
    if (tid < 64) {                    // tid<64 == wave 0: shfl scan is safe
        int val = dh2[tid];
        int inc = val;
        #pragma unroll
        for (int d = 1; d < 64; d <<= 1) {
            int up = __shfl_up(inc, d, 64);
            if (tid >= d) inc += up;
        }
        dh2[tid] = inc - val;          // exclusive base per bin
    }
    __syncthreads();
    if (valid) {
        int r = atomicAdd(&dh2[bin], 1);
        perm[c * 1024 + r] = node;
    }
    __syncthreads();

    // final row-grouped epk scatter (lex consumed as cursors)
    for (int i = tid; i < m; i += 1024) {
        int2 s = stag[cb + i];
        int pos = atomicAdd(&lex[s.y], 1);
        epk[cb + pos] = (unsigned)s.x;
    }
}

// ---------------------------------------------------------------------------
// One-time: repack W_gc into MFMA B-fragment order, bf16.
// ---------------------------------------------------------------------------
__global__ __launch_bounds__(256) void k_prep_w(const float* __restrict__ W,
                                                unsigned short* __restrict__ WB) {
    for (int idx = threadIdx.x; idx < 18 * 64; idx += 256) {
        int grp = idx >> 6;
        int lane = idx & 63;
        int t = grp / 3, s = grp - t * 3;
        int n = t * 16 + (lane & 15);
        int k0 = s * 32 + (lane >> 4) * 8;
        unsigned short* dst = WB + (size_t)idx * 8;
        #pragma unroll
        for (int j = 0; j < 8; ++j)
            dst[j] = f2bf(W[(k0 + j) * D_FEAT + n]);
    }
}

// ---------------------------------------------------------------------------
// One-time: f32 -> bf16 row conversion (x at iteration 0)
// ---------------------------------------------------------------------------
__global__ __launch_bounds__(256) void k_cvt_bf16(const float* __restrict__ src,
                                                  unsigned short* __restrict__ dst,
                                                  int n8) {
    int g = blockIdx.x * 256 + threadIdx.x;
    if (g >= n8) return;
    const float4* s4 = (const float4*)src + (size_t)g * 2;
    float4 x0 = s4[0], x1 = s4[1];
    float vals[8] = {x0.x, x0.y, x0.z, x0.w, x1.x, x1.y, x1.z, x1.w};
    uint4 pk; unsigned* pku = (unsigned*)&pk;
    #pragma unroll
    for (int w2 = 0; w2 < 4; ++w2) {
        unsigned lo = f2bf(vals[w2 * 2 + 0]);
        unsigned hi = f2bf(vals[w2 * 2 + 1]);
        pku[w2] = lo | (hi << 16);
    }
    *(uint4*)(dst + (size_t)g * 8) = pk;
}

// ---------------------------------------------------------------------------
// Kernel 1: support(fp8, 96B rows) = hb(bf16) @ WB(bf16) via MFMA 16x16x32.
// ---------------------------------------------------------------------------
__global__ __launch_bounds__(256) void k_matmul_mfma(
        const unsigned short* __restrict__ hb,
        const unsigned short* __restrict__ WB,
        unsigned char* __restrict__ support) {
    __shared__ float sm[64 * 100];
    int tid = threadIdx.x;
    int wave = tid >> 6, lane = tid & 63;
    int q = lane >> 4, c = lane & 15;
    int m0 = blockIdx.x * 64 + wave * 16;

    if (m0 < N_NODES) {
        const unsigned short* arow = hb + (size_t)(m0 + c) * D_FEAT + q * 8;
        bf16x8 a0 = *(const bf16x8*)(arow);
        bf16x8 a1 = *(const bf16x8*)(arow + 32);
        bf16x8 a2 = *(const bf16x8*)(arow + 64);
        #pragma unroll
        for (int t = 0; t < 6; ++t) {
            const unsigned short* bp = WB + ((size_t)(t * 3) * 64 + lane) * 8;
            bf16x8 b0 = *(const bf16x8*)(bp);
            bf16x8 b1 = *(const bf16x8*)(bp + 64 * 8);
            bf16x8 b2 = *(const bf16x8*)(bp + 128 * 8);
            f32x4 acc = {0.f, 0.f, 0.f, 0.f};
            acc = __builtin_amdgcn_mfma_f32_16x16x32_bf16(a0, b0, acc, 0, 0, 0);
            acc = __builtin_amdgcn_mfma_f32_16x16x32_bf16(a1, b1, acc, 0, 0, 0);
            acc = __builtin_amdgcn_mfma_f32_16x16x32_bf16(a2, b2, acc, 0, 0, 0);
            #pragma unroll
            for (int r = 0; r < 4; ++r)
                sm[(wave * 16 + q * 4 + r) * 100 + t * 16 + c] = acc[r];
        }
    }
    __syncthreads();

    #pragma unroll
    for (int oo = 0; oo < 3; ++oo) {
        int o = tid + oo * 256;
        int row = o / 12;
        int cb = (o - row * 12) * 8;
        int grow = blockIdx.x * 64 + row;
        if (grow < N_NODES) {
            const float* sp = sm + row * 100 + cb;
            uint2 pk;
            pk.x = fp8x4_enc(sp[0], sp[1], sp[2], sp[3]);
            pk.y = fp8x4_enc(sp[4], sp[5], sp[6], sp[7]);
            *(uint2*)(support + (size_t)grow * D_FEAT + cb) = pk;
        }
    }
}

// ---------------------------------------------------------------------------
// Kernel 2 (fused agg+combine): 6 threads/node, 16 fp8 cols (16B load) each.
// bf16 state, in place. Node order = within-chunk degree-sorted perm
// (equal-degree waves; h/off locality preserved per 1024-node chunk).
// ---------------------------------------------------------------------------
__global__ __launch_bounds__(192) void k_agg(const int* __restrict__ off,
                                             const int* __restrict__ perm,
                                             const unsigned* __restrict__ epk,
                                             const unsigned char* __restrict__ support,
                                             const unsigned short* hin,
                                             const float* __restrict__ b,
                                             unsigned short* hout) {
    int gid = blockIdx.x * 192 + threadIdx.x;
    int ni = gid / 6;
    int q = gid % 6;             // 16-col group
    if (ni >= N_NODES) return;
    int n = perm[ni];

    int s = off[n];
    int e = off[n + 1];

    float acc[16];
    #pragma unroll
    for (int j = 0; j < 16; ++j) acc[j] = 0.0f;

    int i = s;
    for (; i < e && (i & 3); ++i) {
        unsigned p = epk[i];
        float v = __uint_as_float(p & 0xFFFF0000u);
        uint4 r = *(const uint4*)(support + (size_t)(p & 0xFFFFu) * D_FEAT + q * 16);
        float f[16];
        fp8x4_dec(r.x, f); fp8x4_dec(r.y, f + 4);
        fp8x4_dec(r.z, f + 8); fp8x4_dec(r.w, f + 12);
        #pragma unroll
        for (int j = 0; j < 16; ++j) acc[j] = fmaf(f[j], v, acc[j]);
    }
    for (; i + 4 <= e; i += 4) {
        uint4 pq = *(const uint4*)(epk + i);
        const unsigned* pp = (const unsigned*)&pq;
        uint4 r0 = *(const uint4*)(support + (size_t)(pp[0] & 0xFFFFu) * D_FEAT + q * 16);
        uint4 r1 = *(const uint4*)(support + (size_t)(pp[1] & 0xFFFFu) * D_FEAT + q * 16);
        uint4 r2 = *(const uint4*)(support + (size_t)(pp[2] & 0xFFFFu) * D_FEAT + q * 16);
        uint4 r3 = *(const uint4*)(support + (size_t)(pp[3] & 0xFFFFu) * D_FEAT + q * 16);
        float v0 = __uint_as_float(pp[0] & 0xFFFF0000u);
        float v1 = __uint_as_float(pp[1] & 0xFFFF0000u);
        float v2 = __uint_as_float(pp[2] & 0xFFFF0000u);
        float v3 = __uint_as_float(pp[3] & 0xFFFF0000u);
        float f[16];
        fp8x4_dec(r0.x, f); fp8x4_dec(r0.y, f + 4);
        fp8x4_dec(r0.z, f + 8); fp8x4_dec(r0.w, f + 12);
        #pragma unroll
        for (int j = 0; j < 16; ++j) acc[j] = fmaf(f[j], v0, acc[j]);
        fp8x4_dec(r1.x, f); fp8x4_dec(r1.y, f + 4);
        fp8x4_dec(r1.z, f + 8); fp8x4_dec(r1.w, f + 12);
        #pragma unroll
        for (int j = 0; j < 16; ++j) acc[j] = fmaf(f[j], v1, acc[j]);
        fp8x4_dec(r2.x, f); fp8x4_dec(r2.y, f + 4);
        fp8x4_dec(r2.z, f + 8); fp8x4_dec(r2.w, f + 12);
        #pragma unroll
        for (int j = 0; j < 16; ++j) acc[j] = fmaf(f[j], v2, acc[j]);
        fp8x4_dec(r3.x, f); fp8x4_dec(r3.y, f + 4);
        fp8x4_dec(r3.z, f + 8); fp8x4_dec(r3.w, f + 12);
        #pragma unroll
        for (int j = 0; j < 16; ++j) acc[j] = fmaf(f[j], v3, acc[j]);
    }
    for (; i < e; ++i) {
        unsigned p = epk[i];
        float v = __uint_as_float(p & 0xFFFF0000u);
        uint4 r = *(const uint4*)(support + (size_t)(p & 0xFFFFu) * D_FEAT + q * 16);
        float f[16];
        fp8x4_dec(r.x, f); fp8x4_dec(r.y, f + 4);
        fp8x4_dec(r.z, f + 8); fp8x4_dec(r.w, f + 12);
        #pragma unroll
        for (int j = 0; j < 16; ++j) acc[j] = fmaf(f[j], v, acc[j]);
    }

    // skip + bias + relu, bf16 state in/out (16 cols)
    const unsigned short* hrow = hin + (size_t)n * D_FEAT + q * 16;
    uint4 hq0 = *(const uint4*)(hrow);
    uint4 hq1 = *(const uint4*)(hrow + 8);
    const unsigned* hu0 = (const unsigned*)&hq0;
    const unsigned* hu1 = (const unsigned*)&hq1;
    const float* brow = b + q * 16;
    float og[16];
    #pragma unroll
    for (int w2 = 0; w2 < 4; ++w2) {
        float h0 = __uint_as_float(hu0[w2] << 16);
        float h1 = __uint_as_float(hu0[w2] & 0xFFFF0000u);
        og[w2*2+0] = fmaxf(0.5f * h0 + 0.5f * (acc[w2*2+0] + brow[w2*2+0]), 0.0f);
        og[w2*2+1] = fmaxf(0.5f * h1 + 0.5f * (acc[w2*2+1] + brow[w2*2+1]), 0.0f);
        float h2 = __uint_as_float(hu1[w2] << 16);
        float h3 = __uint_as_float(hu1[w2] & 0xFFFF0000u);
        og[8+w2*2+0] = fmaxf(0.5f * h2 + 0.5f * (acc[8+w2*2+0] + brow[8+w2*2+0]), 0.0f);
        og[8+w2*2+1] = fmaxf(0.5f * h3 + 0.5f * (acc[8+w2*2+1] + brow[8+w2*2+1]), 0.0f);
    }
    uint4 pk0, pk1;
    unsigned* pu0 = (unsigned*)&pk0;
    unsigned* pu1 = (unsigned*)&pk1;
    #pragma unroll
    for (int w2 = 0; w2 < 4; ++w2) {
        pu0[w2] = (unsigned)f2bf(og[w2*2+0]) | ((unsigned)f2bf(og[w2*2+1]) << 16);
        pu1[w2] = (unsigned)f2bf(og[8+w2*2+0]) | ((unsigned)f2bf(og[8+w2*2+1]) << 16);
    }
    unsigned short* orow = hout + (size_t)n * D_FEAT + q * 16;
    *(uint4*)(orow) = pk0;
    *(uint4*)(orow + 8) = pk1;
}

// ---------------------------------------------------------------------------
// Kernel 3: logits = bf16dec(hb) @ W_lin ; out = log_softmax (f32 math)
// ---------------------------------------------------------------------------
__global__ __launch_bounds__(256) void k_final(const unsigned short* __restrict__ hb,
                                               const float* __restrict__ Wg,
                                               float* __restrict__ out) {
    __shared__ float Wl[D_FEAT * C_CLS];
    {
        const float4* src = (const float4*)Wg;
        float4* dst = (float4*)Wl;
        for (int i = threadIdx.x; i < 960; i += 256) dst[i] = src[i];
    }
    __syncthreads();

    int n = blockIdx.x * 256 + threadIdx.x;
    if (n >= N_NODES) return;

    float acc[C_CLS];
    #pragma unroll
    for (int c = 0; c < C_CLS; ++c) acc[c] = 0.0f;

    const unsigned short* hrow = hb + (size_t)n * D_FEAT;
    for (int g = 0; g < 12; ++g) {
        uint4 hq = *(const uint4*)(hrow + g * 8);
        const unsigned* hu = (const unsigned*)&hq;
        float hv[8];
        #pragma unroll
        for (int w2 = 0; w2 < 4; ++w2) {
            hv[w2*2+0] = __uint_as_float(hu[w2] << 16);
            hv[w2*2+1] = __uint_as_float(hu[w2] & 0xFFFF0000u);
        }
        #pragma unroll
        for (int kk = 0; kk < 8; ++kk) {
            float hs = hv[kk];
            const float* wr = &Wl[(g * 8 + kk) * C_CLS];
            #pragma unroll
            for (int c4 = 0; c4 < 10; ++c4) {
                float4 w = *(const float4*)(wr + c4 * 4);
                acc[c4 * 4 + 0] = fmaf(hs, w.x, acc[c4 * 4 + 0]);
                acc[c4 * 4 + 1] = fmaf(hs, w.y, acc[c4 * 4 + 1]);
                acc[c4 * 4 + 2] = fmaf(hs, w.z, acc[c4 * 4 + 2]);
                acc[c4 * 4 + 3] = fmaf(hs, w.w, acc[c4 * 4 + 3]);
            }
        }
    }

    float m = acc[0];
    #pragma unroll
    for (int c = 1; c < C_CLS; ++c) m = fmaxf(m, acc[c]);
    float s = 0.0f;
    #pragma unroll
    for (int c = 0; c < C_CLS; ++c) s += expf(acc[c] - m);
    float lse = m + logf(s);

    float* orow = out + (size_t)n * C_CLS;
    #pragma unroll
    for (int c4 = 0; c4 < 10; ++c4)
        *(float4*)(orow + c4 * 4) =
            make_float4(acc[c4 * 4 + 0] - lse, acc[c4 * 4 + 1] - lse,
                        acc[c4 * 4 + 2] - lse, acc[c4 * 4 + 3] - lse);
}

// ---------------------------------------------------------------------------
static inline size_t align256(size_t x) { return (x + 255) & ~(size_t)255; }

extern "C" void kernel_launch(void* const* d_in, const int* in_sizes, int n_in,
                              void* d_out, int out_size, void* d_ws, size_t ws_size,
                              hipStream_t stream) {
    const float* x    = (const float*)d_in[0];
    const int*   erow = (const int*)  d_in[1];
    const int*   ecol = (const int*)  d_in[2];
    const float* ev   = (const float*)d_in[3];
    const float* Wgc  = (const float*)d_in[4];
    const float* bgc  = (const float*)d_in[5];
    const float* Wlin = (const float*)d_in[6];
    float* out = (float*)d_out;

    const size_t NF = (size_t)N_NODES * D_FEAT;
    char* ws = (char*)d_ws;
    unsigned short* hb         = (unsigned short*)ws; ws += align256(NF * 2);              // 9.6 MB
    unsigned short* xb         = (unsigned short*)ws; ws += align256(NF * 2);              // 9.6 MB
    unsigned char*  support_f8 = (unsigned char*)ws;  ws += align256(NF);                  // 4.8 MB
    unsigned*       epk        = (unsigned*)ws;       ws += align256((size_t)E_EDGES * 4); // 3.2 MB
    int2*           stag       = (int2*)ws;           ws += align256((size_t)E_EDGES * 8); // 6.4 MB
    unsigned short* WB         = (unsigned short*)ws; ws += align256((size_t)18 * 64 * 8 * 2);
    int*            off        = (int*)ws;            ws += align256((size_t)(N_NODES + 1) * 4);
    int*            perm       = (int*)ws;            ws += align256((size_t)N_NODES * 4);
    int*            cm         = (int*)ws;            ws += align256((size_t)NCHUNK * NB * 4);

    // ---- one-time prep + atomic-free CSR build (+ within-chunk degree sort) ----
    k_prep_w      <<<1, 256, 0, stream>>>(Wgc, WB);
    k_cvt_bf16    <<<(int)((NF / 8 + 255) / 256), 256, 0, stream>>>(x, xb, (int)(NF / 8));
    k_count       <<<NB, 256, 0, stream>>>(erow, cm);
    k_cscan       <<<1, 1024, 0, stream>>>(cm);
    k_scatter_runs<<<NB, 256, 0, stream>>>(erow, ecol, ev, cm, stag);
    k_chunk_csr   <<<NCHUNK, 1024, 0, stream>>>(stag, cm, epk, off, perm);

    // ---- 8 GCN iterations (bf16 state hb, in-place) ----
    const int g_mm = (N_NODES + 63) / 64;
    const int g_ag = (N_NODES * 6 + 191) / 192;
    for (int it = 0; it < N_ITER; ++it) {
        const unsigned short* hin = (it == 0) ? xb : hb;
        k_matmul_mfma<<<g_mm, 256, 0, stream>>>(hin, WB, support_f8);
        k_agg        <<<g_ag, 192, 0, stream>>>(off, perm, epk, support_f8, hin, bgc, hb);
    }
    k_final<<<(N_NODES + 255) / 256, 256, 0, stream>>>(hb, Wlin, out);
}

// Round 12
// 375.842 us; speedup vs baseline: 1.1668x; 1.0492x over previous
//
#include <hip/hip_runtime.h>

#define N_NODES 50000
#define E_EDGES 800000
#define D_FEAT  96
#define C_CLS   40
#define N_ITER  8

#define NCHUNK 49          // ceil(50000/1024) node chunks
#define NB     256         // edge-partition blocks
#define EPB    3125        // edges per block (256*3125 = 800000 exactly)

typedef short bf16x8 __attribute__((ext_vector_type(8)));
typedef float f32x4  __attribute__((ext_vector_type(4)));
typedef float f32x2  __attribute__((ext_vector_type(2)));

#if defined(__has_builtin)
#if __has_builtin(__builtin_amdgcn_cvt_pk_f32_fp8) && __has_builtin(__builtin_amdgcn_cvt_pk_fp8_f32)
#define HAVE_FP8_CVT 1
#endif
#endif
#ifndef HAVE_FP8_CVT
#define HAVE_FP8_CVT 0
#endif

// bf16 helpers (RNE)
static __device__ __forceinline__ unsigned short f2bf(float f) {
    unsigned u = __float_as_uint(f);
    u = (u + 0x7FFF + ((u >> 16) & 1)) >> 16;
    return (unsigned short)u;
}

// ---- fp8 e4m3fn manual fallback ----
static __device__ __forceinline__ unsigned f32_to_fp8_manual(float f) {
    unsigned u = __float_as_uint(f);
    unsigned s = u >> 31;
    int e8 = (int)((u >> 23) & 0xFF) - 127 + 7;
    unsigned m23 = u & 0x7FFFFF;
    if (e8 <= 0) return s << 7;
    if (e8 >= 15) return (s << 7) | 0x7E;
    unsigned m = m23 >> 20;
    unsigned rem = m23 & 0xFFFFF;
    if (rem > 0x80000u || (rem == 0x80000u && (m & 1))) {
        m++;
        if (m == 8) { m = 0; e8++; if (e8 >= 15) return (s << 7) | 0x7E; }
    }
    return (s << 7) | ((unsigned)e8 << 3) | m;
}
static __device__ __forceinline__ float fp8_to_f32_manual(unsigned b) {
    unsigned s = (b >> 7) & 1, e = (b >> 3) & 0xF, m = b & 7;
    if (e == 0) return 0.0f;
    return __uint_as_float((s << 31) | ((e + 120) << 23) | (m << 20));
}
static __device__ __forceinline__ void fp8x4_dec(unsigned w, float* o) {
#if HAVE_FP8_CVT
    f32x2 lo = __builtin_amdgcn_cvt_pk_f32_fp8(w, false);
    f32x2 hi = __builtin_amdgcn_cvt_pk_f32_fp8(w, true);
    o[0] = lo[0]; o[1] = lo[1]; o[2] = hi[0]; o[3] = hi[1];
#else
    o[0] = fp8_to_f32_manual(w & 0xFF);
    o[1] = fp8_to_f32_manual((w >> 8) & 0xFF);
    o[2] = fp8_to_f32_manual((w >> 16) & 0xFF);
    o[3] = fp8_to_f32_manual((w >> 24) & 0xFF);
#endif
}
static __device__ __forceinline__ unsigned fp8x4_enc(float a, float b, float c, float d) {
#if HAVE_FP8_CVT
    unsigned w = __builtin_amdgcn_cvt_pk_fp8_f32(a, b, 0, false);
    w = __builtin_amdgcn_cvt_pk_fp8_f32(c, d, (int)w, true);
    return w;
#else
    return f32_to_fp8_manual(a) | (f32_to_fp8_manual(b) << 8) |
           (f32_to_fp8_manual(c) << 16) | (f32_to_fp8_manual(d) << 24);
#endif
}

// ---------------------------------------------------------------------------
// CSR phase A: per-block LDS histogram over 49 node-chunks -> cm[c*NB + b]
// ---------------------------------------------------------------------------
__global__ __launch_bounds__(256) void k_count(const int* __restrict__ erow,
                                               int* __restrict__ cm) {
    __shared__ int lcnt[NCHUNK];
    int b = blockIdx.x, tid = threadIdx.x;
    if (tid < NCHUNK) lcnt[tid] = 0;
    __syncthreads();
    int base = b * EPB;
    for (int i = tid; i < EPB; i += 256)
        atomicAdd(&lcnt[erow[base + i] >> 10], 1);
    __syncthreads();
    if (tid < NCHUNK) cm[tid * NB + b] = lcnt[tid];
}

// ---------------------------------------------------------------------------
// CSR phase B: in-place exclusive scan of cm (12544 ints), one block
// ---------------------------------------------------------------------------
__global__ __launch_bounds__(1024) void k_cscan(int* __restrict__ cm) {
    __shared__ int sb[1024];
    const int TOT = NCHUNK * NB;
    const int PER = 13;
    int tid = threadIdx.x;
    int base = tid * PER;
    int v[PER];
    int s = 0;
    #pragma unroll
    for (int j = 0; j < PER; ++j) {
        int idx = base + j;
        v[j] = (idx < TOT) ? cm[idx] : 0;
        s += v[j];
    }
    sb[tid] = s;
    __syncthreads();
    for (int d = 1; d < 1024; d <<= 1) {
        int t = (tid >= d) ? sb[tid - d] : 0;
        __syncthreads();
        sb[tid] += t;
        __syncthreads();
    }
    int ex = sb[tid] - s;
    #pragma unroll
    for (int j = 0; j < PER; ++j) {
        int idx = base + j;
        if (idx < TOT) { cm[idx] = ex; ex += v[j]; }
    }
}

// ---------------------------------------------------------------------------
// CSR phase C: scatter (colval, rowlocal) into chunk-major staging runs
// ---------------------------------------------------------------------------
__global__ __launch_bounds__(256) void k_scatter_runs(const int* __restrict__ erow,
                                                      const int* __restrict__ ecol,
                                                      const float* __restrict__ ev,
                                                      const int* __restrict__ cm,
                                                      int2* __restrict__ stag) {
    __shared__ int lcur[NCHUNK];
    int b = blockIdx.x, tid = threadIdx.x;
    if (tid < NCHUNK) lcur[tid] = cm[tid * NB + b];
    __syncthreads();
    int base = b * EPB;
    for (int i = tid; i < EPB; i += 256) {
        int e = base + i;
        int r = erow[e];
        int c = r >> 10;
        int pos = atomicAdd(&lcur[c], 1);
        int2 s;
        s.x = (int)((unsigned)(ecol[e] & 0xFFFF) | ((unsigned)f2bf(ev[e]) << 16));
        s.y = r & 1023;
        stag[pos] = s;
    }
}

// ---------------------------------------------------------------------------
// CSR phase D: per-chunk LDS histogram -> scan -> off[] + row-grouped epk
// ---------------------------------------------------------------------------
__global__ __launch_bounds__(1024) void k_chunk_csr(const int2* __restrict__ stag,
                                                    const int* __restrict__ cm,
                                                    unsigned* __restrict__ epk,
                                                    int* __restrict__ off) {
    __shared__ int lh[1024];
    __shared__ int lex[1024];
    __shared__ int sb[1024];
    int c = blockIdx.x, tid = threadIdx.x;
    int cb = cm[c * NB];
    int ce = (c + 1 < NCHUNK) ? cm[(c + 1) * NB] : E_EDGES;
    int m = ce - cb;

    lh[tid] = 0;
    __syncthreads();
    for (int i = tid; i < m; i += 1024) {
        int2 s = stag[cb + i];
        atomicAdd(&lh[s.y], 1);
    }
    __syncthreads();
    int v = lh[tid];
    sb[tid] = v;
    __syncthreads();
    for (int d = 1; d < 1024; d <<= 1) {
        int t = (tid >= d) ? sb[tid - d] : 0;
        __syncthreads();
        sb[tid] += t;
        __syncthreads();
    }
    int ex = sb[tid] - v;
    lex[tid] = ex;
    int node = c * 1024 + tid;
    if (node < N_NODES) off[node] = cb + ex;
    if (c == NCHUNK - 1 && tid == 0) off[N_NODES] = E_EDGES;
    __syncthreads();
    for (int i = tid; i < m; i += 1024) {
        int2 s = stag[cb + i];
        int pos = atomicAdd(&lex[s.y], 1);
        epk[cb + pos] = (unsigned)s.x;
    }
}

// ---------------------------------------------------------------------------
// One-time: repack W_gc into MFMA B-fragment order, bf16.
// ---------------------------------------------------------------------------
__global__ __launch_bounds__(256) void k_prep_w(const float* __restrict__ W,
                                                unsigned short* __restrict__ WB) {
    for (int idx = threadIdx.x; idx < 18 * 64; idx += 256) {
        int grp = idx >> 6;
        int lane = idx & 63;
        int t = grp / 3, s = grp - t * 3;
        int n = t * 16 + (lane & 15);
        int k0 = s * 32 + (lane >> 4) * 8;
        unsigned short* dst = WB + (size_t)idx * 8;
        #pragma unroll
        for (int j = 0; j < 8; ++j)
            dst[j] = f2bf(W[(k0 + j) * D_FEAT + n]);
    }
}

// ---------------------------------------------------------------------------
// One-time: f32 -> bf16 row conversion (x at iteration 0)
// ---------------------------------------------------------------------------
__global__ __launch_bounds__(256) void k_cvt_bf16(const float* __restrict__ src,
                                                  unsigned short* __restrict__ dst,
                                                  int n8) {
    int g = blockIdx.x * 256 + threadIdx.x;
    if (g >= n8) return;
    const float4* s4 = (const float4*)src + (size_t)g * 2;
    float4 x0 = s4[0], x1 = s4[1];
    float vals[8] = {x0.x, x0.y, x0.z, x0.w, x1.x, x1.y, x1.z, x1.w};
    uint4 pk; unsigned* pku = (unsigned*)&pk;
    #pragma unroll
    for (int w2 = 0; w2 < 4; ++w2) {
        unsigned lo = f2bf(vals[w2 * 2 + 0]);
        unsigned hi = f2bf(vals[w2 * 2 + 1]);
        pku[w2] = lo | (hi << 16);
    }
    *(uint4*)(dst + (size_t)g * 8) = pk;
}

// ---------------------------------------------------------------------------
// Kernel 1: support(fp8, 96B rows) = hb(bf16) @ WB(bf16) via MFMA 16x16x32.
// ---------------------------------------------------------------------------
__global__ __launch_bounds__(256) void k_matmul_mfma(
        const unsigned short* __restrict__ hb,
        const unsigned short* __restrict__ WB,
        unsigned char* __restrict__ support) {
    __shared__ float sm[64 * 100];
    int tid = threadIdx.x;
    int wave = tid >> 6, lane = tid & 63;
    int q = lane >> 4, c = lane & 15;
    int m0 = blockIdx.x * 64 + wave * 16;

    if (m0 < N_NODES) {
        const unsigned short* arow = hb + (size_t)(m0 + c) * D_FEAT + q * 8;
        bf16x8 a0 = *(const bf16x8*)(arow);
        bf16x8 a1 = *(const bf16x8*)(arow + 32);
        bf16x8 a2 = *(const bf16x8*)(arow + 64);
        #pragma unroll
        for (int t = 0; t < 6; ++t) {
            const unsigned short* bp = WB + ((size_t)(t * 3) * 64 + lane) * 8;
            bf16x8 b0 = *(const bf16x8*)(bp);
            bf16x8 b1 = *(const bf16x8*)(bp + 64 * 8);
            bf16x8 b2 = *(const bf16x8*)(bp + 128 * 8);
            f32x4 acc = {0.f, 0.f, 0.f, 0.f};
            acc = __builtin_amdgcn_mfma_f32_16x16x32_bf16(a0, b0, acc, 0, 0, 0);
            acc = __builtin_amdgcn_mfma_f32_16x16x32_bf16(a1, b1, acc, 0, 0, 0);
            acc = __builtin_amdgcn_mfma_f32_16x16x32_bf16(a2, b2, acc, 0, 0, 0);
            #pragma unroll
            for (int r = 0; r < 4; ++r)
                sm[(wave * 16 + q * 4 + r) * 100 + t * 16 + c] = acc[r];
        }
    }
    __syncthreads();

    #pragma unroll
    for (int oo = 0; oo < 3; ++oo) {
        int o = tid + oo * 256;
        int row = o / 12;
        int cb = (o - row * 12) * 8;
        int grow = blockIdx.x * 64 + row;
        if (grow < N_NODES) {
            const float* sp = sm + row * 100 + cb;
            uint2 pk;
            pk.x = fp8x4_enc(sp[0], sp[1], sp[2], sp[3]);
            pk.y = fp8x4_enc(sp[4], sp[5], sp[6], sp[7]);
            *(uint2*)(support + (size_t)grow * D_FEAT + cb) = pk;
        }
    }
}

// ---------------------------------------------------------------------------
// Kernel 2 (fused agg+combine): 6 threads/node, 16 fp8 cols (16B load) each.
// bf16 state, in place. Natural node order.
// ---------------------------------------------------------------------------
__global__ __launch_bounds__(192) void k_agg(const int* __restrict__ off,
                                             const unsigned* __restrict__ epk,
                                             const unsigned char* __restrict__ support,
                                             const unsigned short* hin,
                                             const float* __restrict__ b,
                                             unsigned short* hout) {
    int gid = blockIdx.x * 192 + threadIdx.x;
    int n = gid / 6;
    int q = gid % 6;             // 16-col group
    if (n >= N_NODES) return;

    int s = off[n];
    int e = off[n + 1];

    float acc[16];
    #pragma unroll
    for (int j = 0; j < 16; ++j) acc[j] = 0.0f;

    int i = s;
    for (; i < e && (i & 3); ++i) {
        unsigned p = epk[i];
        float v = __uint_as_float(p & 0xFFFF0000u);
        uint4 r = *(const uint4*)(support + (size_t)(p & 0xFFFFu) * D_FEAT + q * 16);
        float f[16];
        fp8x4_dec(r.x, f); fp8x4_dec(r.y, f + 4);
        fp8x4_dec(r.z, f + 8); fp8x4_dec(r.w, f + 12);
        #pragma unroll
        for (int j = 0; j < 16; ++j) acc[j] = fmaf(f[j], v, acc[j]);
    }
    for (; i + 4 <= e; i += 4) {
        uint4 pq = *(const uint4*)(epk + i);
        const unsigned* pp = (const unsigned*)&pq;
        uint4 r0 = *(const uint4*)(support + (size_t)(pp[0] & 0xFFFFu) * D_FEAT + q * 16);
        uint4 r1 = *(const uint4*)(support + (size_t)(pp[1] & 0xFFFFu) * D_FEAT + q * 16);
        uint4 r2 = *(const uint4*)(support + (size_t)(pp[2] & 0xFFFFu) * D_FEAT + q * 16);
        uint4 r3 = *(const uint4*)(support + (size_t)(pp[3] & 0xFFFFu) * D_FEAT + q * 16);
        float v0 = __uint_as_float(pp[0] & 0xFFFF0000u);
        float v1 = __uint_as_float(pp[1] & 0xFFFF0000u);
        float v2 = __uint_as_float(pp[2] & 0xFFFF0000u);
        float v3 = __uint_as_float(pp[3] & 0xFFFF0000u);
        float f[16];
        fp8x4_dec(r0.x, f); fp8x4_dec(r0.y, f + 4);
        fp8x4_dec(r0.z, f + 8); fp8x4_dec(r0.w, f + 12);
        #pragma unroll
        for (int j = 0; j < 16; ++j) acc[j] = fmaf(f[j], v0, acc[j]);
        fp8x4_dec(r1.x, f); fp8x4_dec(r1.y, f + 4);
        fp8x4_dec(r1.z, f + 8); fp8x4_dec(r1.w, f + 12);
        #pragma unroll
        for (int j = 0; j < 16; ++j) acc[j] = fmaf(f[j], v1, acc[j]);
        fp8x4_dec(r2.x, f); fp8x4_dec(r2.y, f + 4);
        fp8x4_dec(r2.z, f + 8); fp8x4_dec(r2.w, f + 12);
        #pragma unroll
        for (int j = 0; j < 16; ++j) acc[j] = fmaf(f[j], v2, acc[j]);
        fp8x4_dec(r3.x, f); fp8x4_dec(r3.y, f + 4);
        fp8x4_dec(r3.z, f + 8); fp8x4_dec(r3.w, f + 12);
        #pragma unroll
        for (int j = 0; j < 16; ++j) acc[j] = fmaf(f[j], v3, acc[j]);
    }
    for (; i < e; ++i) {
        unsigned p = epk[i];
        float v = __uint_as_float(p & 0xFFFF0000u);
        uint4 r = *(const uint4*)(support + (size_t)(p & 0xFFFFu) * D_FEAT + q * 16);
        float f[16];
        fp8x4_dec(r.x, f); fp8x4_dec(r.y, f + 4);
        fp8x4_dec(r.z, f + 8); fp8x4_dec(r.w, f + 12);
        #pragma unroll
        for (int j = 0; j < 16; ++j) acc[j] = fmaf(f[j], v, acc[j]);
    }

    // skip + bias + relu, bf16 state in/out (16 cols)
    const unsigned short* hrow = hin + (size_t)n * D_FEAT + q * 16;
    uint4 hq0 = *(const uint4*)(hrow);
    uint4 hq1 = *(const uint4*)(hrow + 8);
    const unsigned* hu0 = (const unsigned*)&hq0;
    const unsigned* hu1 = (const unsigned*)&hq1;
    const float* brow = b + q * 16;
    float og[16];
    #pragma unroll
    for (int w2 = 0; w2 < 4; ++w2) {
        float h0 = __uint_as_float(hu0[w2] << 16);
        float h1 = __uint_as_float(hu0[w2] & 0xFFFF0000u);
        og[w2*2+0] = fmaxf(0.5f * h0 + 0.5f * (acc[w2*2+0] + brow[w2*2+0]), 0.0f);
        og[w2*2+1] = fmaxf(0.5f * h1 + 0.5f * (acc[w2*2+1] + brow[w2*2+1]), 0.0f);
        float h2 = __uint_as_float(hu1[w2] << 16);
        float h3 = __uint_as_float(hu1[w2] & 0xFFFF0000u);
        og[8+w2*2+0] = fmaxf(0.5f * h2 + 0.5f * (acc[8+w2*2+0] + brow[8+w2*2+0]), 0.0f);
        og[8+w2*2+1] = fmaxf(0.5f * h3 + 0.5f * (acc[8+w2*2+1] + brow[8+w2*2+1]), 0.0f);
    }
    uint4 pk0, pk1;
    unsigned* pu0 = (unsigned*)&pk0;
    unsigned* pu1 = (unsigned*)&pk1;
    #pragma unroll
    for (int w2 = 0; w2 < 4; ++w2) {
        pu0[w2] = (unsigned)f2bf(og[w2*2+0]) | ((unsigned)f2bf(og[w2*2+1]) << 16);
        pu1[w2] = (unsigned)f2bf(og[8+w2*2+0]) | ((unsigned)f2bf(og[8+w2*2+1]) << 16);
    }
    unsigned short* orow = hout + (size_t)n * D_FEAT + q * 16;
    *(uint4*)(orow) = pk0;
    *(uint4*)(orow + 8) = pk1;
}

// ---------------------------------------------------------------------------
// Kernel 3: logits = bf16dec(hb) @ W_lin ; out = log_softmax (f32 math)
// ---------------------------------------------------------------------------
__global__ __launch_bounds__(256) void k_final(const unsigned short* __restrict__ hb,
                                               const float* __restrict__ Wg,
                                               float* __restrict__ out) {
    __shared__ float Wl[D_FEAT * C_CLS];
    {
        const float4* src = (const float4*)Wg;
        float4* dst = (float4*)Wl;
        for (int i = threadIdx.x; i < 960; i += 256) dst[i] = src[i];
    }
    __syncthreads();

    int n = blockIdx.x * 256 + threadIdx.x;
    if (n >= N_NODES) return;

    float acc[C_CLS];
    #pragma unroll
    for (int c = 0; c < C_CLS; ++c) acc[c] = 0.0f;

    const unsigned short* hrow = hb + (size_t)n * D_FEAT;
    for (int g = 0; g < 12; ++g) {
        uint4 hq = *(const uint4*)(hrow + g * 8);
        const unsigned* hu = (const unsigned*)&hq;
        float hv[8];
        #pragma unroll
        for (int w2 = 0; w2 < 4; ++w2) {
            hv[w2*2+0] = __uint_as_float(hu[w2] << 16);
            hv[w2*2+1] = __uint_as_float(hu[w2] & 0xFFFF0000u);
        }
        #pragma unroll
        for (int kk = 0; kk < 8; ++kk) {
            float hs = hv[kk];
            const float* wr = &Wl[(g * 8 + kk) * C_CLS];
            #pragma unroll
            for (int c4 = 0; c4 < 10; ++c4) {
                float4 w = *(const float4*)(wr + c4 * 4);
                acc[c4 * 4 + 0] = fmaf(hs, w.x, acc[c4 * 4 + 0]);
                acc[c4 * 4 + 1] = fmaf(hs, w.y, acc[c4 * 4 + 1]);
                acc[c4 * 4 + 2] = fmaf(hs, w.z, acc[c4 * 4 + 2]);
                acc[c4 * 4 + 3] = fmaf(hs, w.w, acc[c4 * 4 + 3]);
            }
        }
    }

    float m = acc[0];
    #pragma unroll
    for (int c = 1; c < C_CLS; ++c) m = fmaxf(m, acc[c]);
    float s = 0.0f;
    #pragma unroll
    for (int c = 0; c < C_CLS; ++c) s += expf(acc[c] - m);
    float lse = m + logf(s);

    float* orow = out + (size_t)n * C_CLS;
    #pragma unroll
    for (int c4 = 0; c4 < 10; ++c4)
        *(float4*)(orow + c4 * 4) =
            make_float4(acc[c4 * 4 + 0] - lse, acc[c4 * 4 + 1] - lse,
                        acc[c4 * 4 + 2] - lse, acc[c4 * 4 + 3] - lse);
}

// ---------------------------------------------------------------------------
static inline size_t align256(size_t x) { return (x + 255) & ~(size_t)255; }

extern "C" void kernel_launch(void* const* d_in, const int* in_sizes, int n_in,
                              void* d_out, int out_size, void* d_ws, size_t ws_size,
                              hipStream_t stream) {
    const float* x    = (const float*)d_in[0];
    const int*   erow = (const int*)  d_in[1];
    const int*   ecol = (const int*)  d_in[2];
    const float* ev   = (const float*)d_in[3];
    const float* Wgc  = (const float*)d_in[4];
    const float* bgc  = (const float*)d_in[5];
    const float* Wlin = (const float*)d_in[6];
    float* out = (float*)d_out;

    const size_t NF = (size_t)N_NODES * D_FEAT;
    char* ws = (char*)d_ws;
    unsigned short* hb         = (unsigned short*)ws; ws += align256(NF * 2);              // 9.6 MB
    unsigned short* xb         = (unsigned short*)ws; ws += align256(NF * 2);              // 9.6 MB
    unsigned char*  support_f8 = (unsigned char*)ws;  ws += align256(NF);                  // 4.8 MB
    unsigned*       epk        = (unsigned*)ws;       ws += align256((size_t)E_EDGES * 4); // 3.2 MB
    int2*           stag       = (int2*)ws;           ws += align256((size_t)E_EDGES * 8); // 6.4 MB
    unsigned short* WB         = (unsigned short*)ws; ws += align256((size_t)18 * 64 * 8 * 2);
    int*            off        = (int*)ws;            ws += align256((size_t)(N_NODES + 1) * 4);
    int*            cm         = (int*)ws;            ws += align256((size_t)NCHUNK * NB * 4);

    // ---- one-time prep + atomic-free CSR build ----
    k_prep_w      <<<1, 256, 0, stream>>>(Wgc, WB);
    k_cvt_bf16    <<<(int)((NF / 8 + 255) / 256), 256, 0, stream>>>(x, xb, (int)(NF / 8));
    k_count       <<<NB, 256, 0, stream>>>(erow, cm);
    k_cscan       <<<1, 1024, 0, stream>>>(cm);
    k_scatter_runs<<<NB, 256, 0, stream>>>(erow, ecol, ev, cm, stag);
    k_chunk_csr   <<<NCHUNK, 1024, 0, stream>>>(stag, cm, epk, off);

    // ---- 8 GCN iterations (bf16 state hb, in-place) ----
    const int g_mm = (N_NODES + 63) / 64;
    const int g_ag = (N_NODES * 6 + 191) / 192;
    for (int it = 0; it < N_ITER; ++it) {
        const unsigned short* hin = (it == 0) ? xb : hb;
        k_matmul_mfma<<<g_mm, 256, 0, stream>>>(hin, WB, support_f8);
        k_agg        <<<g_ag, 192, 0, stream>>>(off, epk, support_f8, hin, bgc, hb);
    }
    k_final<<<(N_NODES + 255) / 256, 256, 0, stream>>>(hb, Wlin, out);
}